// Round 22
// baseline (116.996 us; speedup 1.0000x reference)
//
#include <hip/hip_runtime.h>

#define NP_   16384
#define NQ_   8192
#define NB_   2
#define K_    16
#define QPB   16           // queries per block (4 per wave x 4 waves)
#define TPB   256
#define TILE  1024         // points per LDS tile (16KB)
#define NTILES (NP_/TILE)  // 16
#define GPT   (TILE/64)    // 16 group-iterations per tile
#define CBUF  80           // per-query append buffer (15 carry + 64/iter max)

#define IDX_OFF 0
#define RS_OFF  (NB_*NQ_*K_)        // 262144
#define RS_N    (NB_*NQ_+1)         // 16385
#define DST_OFF (RS_OFF + RS_N)     // 278529

typedef unsigned long long ull;
typedef float f32x2 __attribute__((ext_vector_type(2)));

__device__ __forceinline__ int mbcnt64(ull m) {
    return __builtin_amdgcn_mbcnt_hi((unsigned)(m >> 32),
           __builtin_amdgcn_mbcnt_lo((unsigned)m, 0));
}

__global__ __launch_bounds__(TPB, 4) void knn_kernel(const float* __restrict__ pts,
                                                     const float* __restrict__ qrs,
                                                     float* __restrict__ out)
{
    // Validated exact-match formula (R6):
    //   sq, sp : forward sum, separate mul/add rounds
    //   ip     : forward FMA chain  fma(z,qz, fma(y,qy, round(x*qx)))
    //   d      : fmaf(-2, ip, sq+sp)
    // Packed components are IEEE-identical per component -> bit-exact.
    #pragma clang fp contract(off)

    __shared__ float4 tile[TILE];        // 16KB
    __shared__ float2 buf[QPB][CBUF];    // 10KB append buffers

    const int tid  = threadIdx.x;
    const int lane = tid & 63;
    const int s    = lane & 15;               // rank this lane owns
    const int g    = lane >> 4;               // query slot within wave (0..3)
    const int bq   = tid >> 4;                // block-level id of OWN query
    const int gq   = blockIdx.x * QPB + bq;
    const int batch = gq >> 13;
    const int gofs  = batch * NP_;
    const float* pb = pts + (size_t)gofs * 3;
    const int qb   = (tid >> 6) << 2;         // wave's first block-level query

    float qxv[4], qyv[4], qzv[4], sqv[4];
    #pragma unroll
    for (int qi = 0; qi < 4; ++qi) {
        const float* qp = qrs + (size_t)(blockIdx.x * QPB + qb + qi) * 3;
        qxv[qi] = qp[0]; qyv[qi] = qp[1]; qzv[qi] = qp[2];
        sqv[qi] = qxv[qi]*qxv[qi] + qyv[qi]*qyv[qi] + qzv[qi]*qzv[qi]; // fwd, no FMA
    }
    const f32x2 qx01 = {qxv[0], qxv[1]}, qx23 = {qxv[2], qxv[3]};
    const f32x2 qy01 = {qyv[0], qyv[1]}, qy23 = {qyv[2], qyv[3]};
    const f32x2 qz01 = {qzv[0], qzv[1]}, qz23 = {qzv[2], qzv[3]};
    const f32x2 sq01 = {sqv[0], sqv[1]}, sq23 = {sqv[2], sqv[3]};
    const f32x2 n2   = {-2.0f, -2.0f};

    const float INF = __int_as_float(0x7f800000);
    float hd = INF; int hi = 0x7fffffff;      // distributed top-16: rank-s of own query
    float th0 = INF, th1 = INF, th2 = INF, th3 = INF, thmax = INF;
    int cnt0 = 0, cnt1 = 0, cnt2 = 0, cnt3 = 0;

    // drain all buffered entries into the distributed lists (wave-uniform)
    auto drain = [&]() {
        int cmax = max(max(cnt0, cnt1), max(cnt2, cnt3));
        int mycnt = (g==0) ? cnt0 : (g==1) ? cnt1 : (g==2) ? cnt2 : cnt3;
        for (int r = 0; r < cmax; r += K_) {
            float nd = INF; int ni = 0x7fffffff;
            int pos = r + s;
            if (pos < mycnt) {
                float2 e = buf[bq][pos];
                nd = e.x; ni = __float_as_int(e.y);
            }
            // bitonic sort-16 ascending by (d, idx) within each 16-lane group
            #pragma unroll
            for (int m = 2; m <= 16; m <<= 1) {
                #pragma unroll
                for (int j = m >> 1; j > 0; j >>= 1) {
                    float od = __shfl_xor(nd, j);
                    int   oi = __shfl_xor(ni, j);
                    bool pl = (od < nd) || (od == nd && oi < ni);
                    bool keepmin = ((s & j) == 0) == ((s & m) == 0);
                    if (keepmin == pl) { nd = od; ni = oi; }
                }
            }
            // Batcher halver vs sorted list: keep min(L[s], N[15-s])
            float od = __shfl_xor(nd, 15);
            int   oi = __shfl_xor(ni, 15);
            bool pl = (od < hd) || (od == hd && oi < hi);
            if (pl) { hd = od; hi = oi; }
            // bitonic cleanup (4 stages, ascending)
            #pragma unroll
            for (int j = 8; j > 0; j >>= 1) {
                float od2 = __shfl_xor(hd, j);
                int   oi2 = __shfl_xor(hi, j);
                bool pl2 = (od2 < hd) || (od2 == hd && oi2 < hi);
                if (((s & j) == 0) == pl2) { hd = od2; hi = oi2; }
            }
        }
        cnt0 = cnt1 = cnt2 = cnt3 = 0;
        th0 = __shfl(hd, 15, 64);             // exact 16th-best per query
        th1 = __shfl(hd, 31, 64);
        th2 = __shfl(hd, 47, 64);
        th3 = __shfl(hd, 63, 64);
        thmax = fmaxf(fmaxf(th0, th1), fmaxf(th2, th3));
    };

    for (int t = 0; t < NTILES; ++t) {
        __syncthreads();
        #pragma unroll
        for (int k = 0; k < TILE/TPB; ++k) {
            int lp = tid + k*TPB;
            int gp = t*TILE + lp;
            float x = pb[gp*3+0], y = pb[gp*3+1], z = pb[gp*3+2];
            float sp = x*x + y*y + z*z;       // fwd, no FMA
            tile[lp] = make_float4(x, y, z, sp);
        }
        __syncthreads();

        // depth-1 software pipeline: ds_read for gi+1 issues before gi's math
        float4 pcur = tile[lane];
        #pragma unroll 2
        for (int gi = 0; gi < GPT; ++gi) {
            float4 pnext = tile[(((gi + 1) & (GPT-1)) << 6) + lane];
            f32x2 x2 = {pcur.x, pcur.x}, y2 = {pcur.y, pcur.y};
            f32x2 z2 = {pcur.z, pcur.z}, sps = {pcur.w, pcur.w};
            f32x2 ip01 = __builtin_elementwise_fma(z2, qz01,
                         __builtin_elementwise_fma(y2, qy01, x2*qx01));
            f32x2 ip23 = __builtin_elementwise_fma(z2, qz23,
                         __builtin_elementwise_fma(y2, qy23, x2*qx23));
            f32x2 d01 = __builtin_elementwise_fma(n2, ip01, sq01 + sps);
            f32x2 d23 = __builtin_elementwise_fma(n2, ip23, sq23 + sps);
            float d0 = d01.x, d1 = d01.y, d2 = d23.x, d3 = d23.y;
            // fast-path gate: superset of the 4 per-query tests (1 cmp)
            float dmin = fminf(fminf(d0, d1), fminf(d2, d3));
            if (__any(dmin <= thmax)) {
                ull m0 = __ballot(d0 <= th0); // <= : tie-safe superset filter
                ull m1 = __ballot(d1 <= th1);
                ull m2 = __ballot(d2 <= th2);
                ull m3 = __ballot(d3 <= th3);
                const float fpid = __int_as_float(t*TILE + (gi << 6) + lane);
                if (m0) {                     // append: slot = cnt + mbcnt(mask)
                    int sl = cnt0 + mbcnt64(m0);
                    if (d0 <= th0) buf[qb+0][sl] = make_float2(d0, fpid);
                    cnt0 += (int)__popcll(m0);
                }
                if (m1) {
                    int sl = cnt1 + mbcnt64(m1);
                    if (d1 <= th1) buf[qb+1][sl] = make_float2(d1, fpid);
                    cnt1 += (int)__popcll(m1);
                }
                if (m2) {
                    int sl = cnt2 + mbcnt64(m2);
                    if (d2 <= th2) buf[qb+2][sl] = make_float2(d2, fpid);
                    cnt2 += (int)__popcll(m2);
                }
                if (m3) {
                    int sl = cnt3 + mbcnt64(m3);
                    if (d3 <= th3) buf[qb+3][sl] = make_float2(d3, fpid);
                    cnt3 += (int)__popcll(m3);
                }
                if ((cnt0 | cnt1 | cnt2 | cnt3) >= K_) drain();
            }
            pcur = pnext;
        }
    }

    drain();                                  // flush leftovers (<16 per query)

    // output: lane s holds rank-s of its query
    out[IDX_OFF + gq*K_ + s] = (float)(hi + gofs);
    out[DST_OFF + gq*K_ + s] = fmaxf(hd, 0.0f);

    // row_splits = arange(16385) * 16, written as float (exact)
    int gt = blockIdx.x * TPB + tid;
    if (gt < RS_N) out[RS_OFF + gt] = (float)(gt * K_);
}

extern "C" void kernel_launch(void* const* d_in, const int* in_sizes, int n_in,
                              void* d_out, int out_size, void* d_ws, size_t ws_size,
                              hipStream_t stream)
{
    const float* pts = (const float*)d_in[0];
    const float* qrs = (const float*)d_in[1];
    float* out = (float*)d_out;
    (void)in_sizes; (void)n_in; (void)out_size; (void)d_ws; (void)ws_size;

    dim3 grid(NB_ * NQ_ / QPB);   // 1024 blocks
    dim3 block(TPB);              // 256 threads
    knn_kernel<<<grid, block, 0, stream>>>(pts, qrs, out);
}